// Round 1
// 143.088 us; speedup vs baseline: 1.0365x; 1.0365x over previous
//
#include <hip/hip_runtime.h>
#include <hip/hip_fp16.h>
#include <math.h>

typedef __attribute__((ext_vector_type(8))) _Float16 half8;
typedef __attribute__((ext_vector_type(4))) float f32x4;

// Problem constants: B=2, C=64, E=4, HLR=WLR=192, scale=2 -> H=W=384
#define HLR_ 192
#define WLR_ 192
#define H_ 384
#define W_ 384
#define LRP (HLR_*WLR_)            // 36864
#define PTILES (LRP/64)            // 576
#define TPX 96                     // pixels per main block (4 tiles/row)
#define NTW (W_/TPX)               // 4
#define IPW 48                     // items per wave (TPX/2 parities)
#define RUN 6                      // items per run-owner (8 owners/wave)

// ws layout (float units):
//   [0 .. 2359296)            fused_t [B][HLR*WLR][C] fp16 (9.4 MB)
//   [2359296 .. +8192)        Kmat: 4 cls x 64 x 64 fp16, K' = I + weT@wc
//   then 8 floats             g_off [4 cls][2]
#define WS_K_OFF 2359296
#define WS_OFF_OFF (WS_K_OFF + 8192)

__device__ __forceinline__ unsigned short f32_f16(float x){
    union { _Float16 h; unsigned short u; } c; c.h = (_Float16)x; return c.u;
}
__device__ __forceinline__ unsigned int pk_f16(float a, float b){
    union { _Float16 h[2]; unsigned int u; } c;
    c.h[0] = (_Float16)a; c.h[1] = (_Float16)b; return c.u;
}
__device__ __forceinline__ half8 splat8(float f){
    _Float16 h = (_Float16)f;
    half8 v = {h,h,h,h,h,h,h,h};
    return v;
}

// ---------------------------------------------------------------------------
// Kernel A (merged): block 0 = precompute (per-class MLP -> routing/offset ->
// K' = I + weT_mix@wc_mix in fp16); blocks 1.. = transpose+downconvert
// fused [B][C][HLR][WLR] fp32 -> fused_t [B][HLR*WLR][C] fp16.
// Transpose is vectorized: f32x4 global loads, packed-fp16 8B stores.
// ---------------------------------------------------------------------------
__global__ __launch_bounds__(256) void prep_kernel(
    const float* __restrict__ fused, unsigned short* __restrict__ fused_t,
    const float* __restrict__ w1, const float* __restrict__ b1,
    const float* __restrict__ w2, const float* __restrict__ b2,
    const float* __restrict__ rw, const float* __restrict__ rb,
    const float* __restrict__ ow, const float* __restrict__ ob,
    const float* __restrict__ WC, const float* __restrict__ WE,
    unsigned short* __restrict__ Kmat, float* __restrict__ g_off)
{
    __shared__ float smem[8912];    // 35.6 KB, unioned between the two paths
    int bid = blockIdx.x;
    int tid = threadIdx.x;

    if (bid == 0) {
        float* sW2 = smem;          // [64][65] = 4160
        float* sRW = smem + 4160;   // [6][64]  = 384
        float* sE1 = smem + 4544;   // [4][64]  = 256
        float* sR  = smem + 4800;   // [4][4]   = 16
        float* sWc = smem + 4816;   // [4][8][64]  = 2048
        float* sWe = smem + 6864;   // [4][64][8]  = 2048

        for (int idx = tid; idx < 4096; idx += 256)
            sW2[(idx>>6)*65 + (idx&63)] = w2[idx];
        sRW[tid] = rw[tid];
        if (tid < 128) sRW[256 + tid] = ow[tid];

        int wave = tid >> 6, lane = tid & 63;   // wave = class = ph*2 + pw
        int ph = wave >> 1, pw = wave & 1;

        float ch = (ph + 0.5f)*0.5f;
        float coor_h = ch - floorf(ch + 0.001f) - 0.5f;
        float cw = (pw + 0.5f)*0.5f;
        float coor_w = cw - floorf(cw + 0.001f) - 0.5f;

        float e1 = w1[lane*4+0]*0.5f + w1[lane*4+1]*0.5f
                 + w1[lane*4+2]*coor_h + w1[lane*4+3]*coor_w + b1[lane];
        sE1[wave*64 + lane] = fmaxf(e1, 0.0f);
        __syncthreads();

        float e2 = b2[lane];
        #pragma unroll 16
        for (int i = 0; i < 64; ++i) e2 += sW2[lane*65 + i] * sE1[wave*64 + i];
        e2 = fmaxf(e2, 0.0f);

        #pragma unroll
        for (int k = 0; k < 6; ++k) {
            float t = sRW[k*64 + lane] * e2;
            #pragma unroll
            for (int m = 1; m <= 32; m <<= 1) t += __shfl_xor(t, m, 64);
            if (lane == 0) {
                if (k < 4) sR[wave*4 + k] = 1.0f/(1.0f + expf(-(t + rb[k])));
                else       g_off[wave*2 + (k-4)] = t + ob[k-4];
            }
        }
        __syncthreads();

        for (int idx = tid; idx < 2048; idx += 256) {
            int cls = idx >> 9, rem = idx & 511;          // rem = o*64 + c
            float r0=sR[cls*4+0], r1=sR[cls*4+1], r2=sR[cls*4+2], r3=sR[cls*4+3];
            sWc[cls*512 + rem] =
                r0*WC[0*512+rem] + r1*WC[1*512+rem] + r2*WC[2*512+rem] + r3*WC[3*512+rem];
        }
        for (int idx = tid; idx < 2048; idx += 256) {
            int cls = idx >> 9, rem = idx & 511;          // rem = c*8 + o
            float r0=sR[cls*4+0], r1=sR[cls*4+1], r2=sR[cls*4+2], r3=sR[cls*4+3];
            sWe[cls*512 + rem] =
                r0*WE[0*512+rem] + r1*WE[1*512+rem] + r2*WE[2*512+rem] + r3*WE[3*512+rem];
        }
        __syncthreads();

        // K'[cls][c][cp] = (c==cp) + sum_o we[c][o]*wc[o][cp]  (identity folded)
        for (int idx = tid; idx < 16384; idx += 256) {
            int cls = idx >> 12, rem = idx & 4095;
            int c = rem >> 6, cp = rem & 63;
            float a = (c == cp) ? 1.0f : 0.0f;
            #pragma unroll
            for (int o = 0; o < 8; ++o)
                a += sWe[cls*512 + c*8 + o] * sWc[cls*512 + o*64 + cp];
            Kmat[idx] = f32_f16(a);
        }
    } else {
        float* tile = smem;   // [64][65]
        int id = bid - 1;
        int b = id / PTILES, pt = id % PTILES;
        int p0 = pt * 64;
        // load: 64 ch x 64 px tile via f32x4 (4 per thread)
        #pragma unroll
        for (int i = 0; i < 4; ++i) {
            int n = tid + i*256;            // 0..1023
            int c = n >> 4, k = (n & 15) << 2;
            f32x4 v = *(const f32x4*)(fused + (size_t)(b*64 + c)*LRP + p0 + k);
            float* tp = tile + c*65 + k;
            tp[0]=v[0]; tp[1]=v[1]; tp[2]=v[2]; tp[3]=v[3];
        }
        __syncthreads();
        // store: per thread 4 channels packed fp16 (8B), 16 threads = 128B row
        int c0 = (tid & 15) << 2, pr = tid >> 4;
        #pragma unroll
        for (int i = 0; i < 4; ++i) {
            int p = pr + i*16;
            uint2 pv;
            pv.x = pk_f16(tile[(c0+0)*65 + p], tile[(c0+1)*65 + p]);
            pv.y = pk_f16(tile[(c0+2)*65 + p], tile[(c0+3)*65 + p]);
            *(uint2*)(fused_t + (((size_t)(b*LRP + p0 + p)) << 6) + c0) = pv;
        }
    }
}

// ---------------------------------------------------------------------------
// Kernel B: main. Block = 96 HR pixels of one row x 2 batches (192 items).
// Grid = 1536 = exactly 6 blocks/CU resident (24 KB LDS, launch_bounds(256,6)).
// Wave w = (batch = w>>1, parity = w&1): 48 same-class items.
// Phase 1: rolling-x bilinear gather from fp16 fused_t — lane group itg
//   (8 owners) owns a 6-item run, 8 channels/lane; 14 dwordx4/lane total.
//   Interp in packed fp16 (v_pk_fma_f16); result is MFMA-ready, no repack.
// sFea LDS layout: slot-major, 128 B/slot, XOR-swizzled 16B chunks
//   (chunk ^ (slot&7)) — conflict-free b128 on both sides.
// Phase 2: per-wave 64x64 K'_cls(A) @ feaT(B) via mfma_f32_16x16x32_f16.
// ---------------------------------------------------------------------------
__global__ __launch_bounds__(256, 6) void main_kernel(
    const unsigned short* __restrict__ fused_t, const unsigned short* __restrict__ Kmat,
    const float* __restrict__ g_off, float* __restrict__ out)
{
    __shared__ unsigned short sFea[4*IPW*64];   // 24576 B (fp16 bits)

    int g = blockIdx.x;
    int xcd = g & 7;
    int t = g >> 3;                 // 0..191
    int q = t >> 2;                 // 0..47
    int wt = t & 3;
    int h = xcd*48 + q;
    int w0 = wt * TPX;
    int tid = threadIdx.x, wave = tid >> 6, lane = tid & 63;
    int b = wave >> 1, par = wave & 1;
    int ph = h & 1, cls = ph*2 + par;

    float off0 = g_off[cls*2 + 0];
    float off1 = g_off[cls*2 + 1];

    // y quantities: wave-uniform
    float py  = (h + 0.5f)*0.5f - 0.5f + off1;
    float y0f = floorf(py);
    float wy  = py - y0f;
    int   y0  = (int)y0f;
    float fy0 = (y0 >= 0  && y0 <= HLR_-1) ? 1.0f : 0.0f;
    float fy1 = (y0 >= -1 && y0 <= HLR_-2) ? 1.0f : 0.0f;
    int   yc0 = min(max(y0, 0), HLR_-1);
    int   yc1 = min(max(y0+1, 0), HLR_-1);
    float omwy = 1.0f - wy;

    // x: px for item i (pixel w = w0 + 2i + par) = pxb + i exactly
    float pxb  = (w0 + par + 0.5f)*0.5f - 0.5f + off0;
    float x0bf = floorf(pxb);
    float wx   = pxb - x0bf;
    int   x0b  = (int)x0bf;
    float omwx = 1.0f - wx;

    // wave-uniform corner weights with y-masks folded in
    float W00 = omwx*omwy*fy0, W01 = wx*omwy*fy0;
    float W10 = omwx*wy  *fy1, W11 = wx*wy  *fy1;

    int itg = lane >> 3;            // run owner 0..7 (6 items each)
    int cg  = lane & 7;             // channel octet 0..7

    const unsigned short* baseB = fused_t + (size_t)b * LRP * 64;
    const unsigned short* r0 = baseB + (size_t)yc0 * WLR_ * 64 + cg*8;
    const unsigned short* r1 = baseB + (size_t)yc1 * WLR_ * 64 + cg*8;
    unsigned short* sW = sFea + wave*IPW*64;

    int xs = x0b + itg*RUN;
    int xc = min(max(xs, 0), WLR_-1);
    half8 p0 = *(const half8*)(r0 + (size_t)xc*64);
    half8 p1 = *(const half8*)(r1 + (size_t)xc*64);
    float fxp = (xs >= 0 && xs <= WLR_-1) ? 1.0f : 0.0f;

    #pragma unroll
    for (int j = 0; j < RUN; ++j) {
        int xn = xs + j + 1;
        float fxn = (xn >= 0 && xn <= WLR_-1) ? 1.0f : 0.0f;
        int xcn = min(max(xn, 0), WLR_-1);
        half8 c0 = *(const half8*)(r0 + (size_t)xcn*64);
        half8 c1 = *(const half8*)(r1 + (size_t)xcn*64);
        half8 v = p0*splat8(W00*fxp);
        v += c0*splat8(W01*fxn);
        v += p1*splat8(W10*fxp);
        v += c1*splat8(W11*fxn);
        int item = itg*RUN + j;
        *(half8*)(sW + (item << 6) + ((cg ^ (item & 7)) << 3)) = v;
        p0 = c0; p1 = c1; fxp = fxn;
    }
    __syncthreads();

    // ---- phase 2 ----
    int lm = lane & 15, lg = lane >> 4;

    const unsigned short* Kc = Kmat + cls*4096;
    half8 Af[4][2];   // A[m][k]: m = out channel
    #pragma unroll
    for (int mt = 0; mt < 4; ++mt)
        #pragma unroll
        for (int kt = 0; kt < 2; ++kt)
            Af[mt][kt] = *(const half8*)(Kc + (mt*16 + lm)*64 + kt*32 + lg*8);

    #pragma unroll
    for (int nt = 0; nt < 3; ++nt) {
        int slot = nt*16 + lm;
        const unsigned short* sb = sFea + (wave*IPW + slot)*64;
        half8 B0 = *(const half8*)(sb + (((0*4 + lg) ^ (slot & 7)) << 3));
        half8 B1 = *(const half8*)(sb + (((1*4 + lg) ^ (slot & 7)) << 3));

        int wc = w0 + 2*slot + par;
        #pragma unroll
        for (int mt = 0; mt < 4; ++mt) {
            f32x4 a = {0.0f, 0.0f, 0.0f, 0.0f};
            a = __builtin_amdgcn_mfma_f32_16x16x32_f16(Af[mt][0], B0, a, 0, 0, 0);
            a = __builtin_amdgcn_mfma_f32_16x16x32_f16(Af[mt][1], B1, a, 0, 0, 0);
            // D[row=c][col=item]; col=lane&15, row=(lane>>4)*4+reg (m89 map)
            int c0r = mt*16 + lg*4;
            float* op = out + (((size_t)(b*64 + c0r)*H_ + h)*W_ + wc);
            op[0*(size_t)(H_*W_)] = a[0];
            op[1*(size_t)(H_*W_)] = a[1];
            op[2*(size_t)(H_*W_)] = a[2];
            op[3*(size_t)(H_*W_)] = a[3];
        }
    }
}

extern "C" void kernel_launch(void* const* d_in, const int* in_sizes, int n_in,
                              void* d_out, int out_size, void* d_ws, size_t ws_size,
                              hipStream_t stream)
{
    const float* fused = (const float*)d_in[1];
    const float* WC    = (const float*)d_in[2];
    const float* WE    = (const float*)d_in[3];
    const float* w1    = (const float*)d_in[4];
    const float* b1    = (const float*)d_in[5];
    const float* w2    = (const float*)d_in[6];
    const float* b2    = (const float*)d_in[7];
    const float* rw    = (const float*)d_in[8];
    const float* rb    = (const float*)d_in[9];
    const float* ow    = (const float*)d_in[10];
    const float* ob    = (const float*)d_in[11];
    (void)in_sizes; (void)n_in; (void)out_size; (void)ws_size;

    float* ws = (float*)d_ws;
    unsigned short* fused_t = (unsigned short*)ws;
    unsigned short* Kmat = (unsigned short*)(ws + WS_K_OFF);
    float* g_off = ws + WS_OFF_OFF;
    float* o = (float*)d_out;

    hipLaunchKernelGGL(prep_kernel, dim3(1 + 2*PTILES), dim3(256), 0, stream,
                       fused, fused_t, w1, b1, w2, b2, rw, rb, ow, ob, WC, WE,
                       Kmat, g_off);
    hipLaunchKernelGGL(main_kernel, dim3(H_*NTW), dim3(256), 0, stream,
                       fused_t, Kmat, g_off, o);
}